// Round 4
// baseline (777.193 us; speedup 1.0000x reference)
//
#include <hip/hip_runtime.h>
#include <stdint.h>

#define IN_F 4096
#define OUT_F 4096
#define SEL_BLOCKS 512

typedef __attribute__((ext_vector_type(8))) __bf16 bf16x8;
typedef __attribute__((ext_vector_type(8))) short short8;
typedef __attribute__((ext_vector_type(4))) float f32x4;

struct SelState {
  unsigned int hist[3 * 2048];
  unsigned int prefix;     // accumulates selected bin bits; after round 2 = threshold bit pattern
  unsigned int remaining;  // k remaining within current prefix
  unsigned int count;
  float sum;
  float scale;             // unused (gemm computes inline); kept for layout
  unsigned int tickets[3];
  unsigned int flags[3];
};

__device__ __forceinline__ unsigned short f2bf_rne(unsigned int u) {
  // round-to-nearest-even fp32 -> bf16 (inputs are finite, no NaN handling needed)
  return (unsigned short)((u + 0x7FFFu + ((u >> 16) & 1u)) >> 16);
}

// cast x to bf16; block 0 also zeroes SelState (incl. tickets/flags) and sets
// remaining=k. Stream order guarantees completion before select_kernel starts.
__global__ void cast_x_kernel(const float4* __restrict__ x, ushort4* __restrict__ xb, int n4,
                              SelState* st, unsigned int k) {
  int t = threadIdx.x;
  if (blockIdx.x == 0) {
    unsigned int* p = (unsigned int*)st;
    for (int i = t; i < (int)(sizeof(SelState) / 4); i += 256) p[i] = 0;
    __syncthreads();
    if (t == 0) st->remaining = k;
  }
  int i = blockIdx.x * blockDim.x + t;
  int stride = gridDim.x * blockDim.x;
  for (; i < n4; i += stride) {
    float4 v = x[i];
    ushort4 o;
    o.x = f2bf_rne(__float_as_uint(v.x));
    o.y = f2bf_rne(__float_as_uint(v.y));
    o.z = f2bf_rne(__float_as_uint(v.z));
    o.w = f2bf_rne(__float_as_uint(v.w));
    xb[i] = o;
  }
}

// Fused radix-select (3 histogram rounds + inline scans) + ternary quantize.
// One persistent kernel, SEL_BLOCKS=512 blocks x 256 thr x 32 KiB LDS: all
// blocks guaranteed resident (>=5 blocks/CU possible by LDS, need 2/CU), so
// device-scope ticket/flag sync cannot deadlock. Per round: local 4x-replicated
// hist -> merge to global -> last-finishing block (ticket) scans and releases a
// flag; all blocks spin (s_sleep) then proceed. All cross-block scalars use
// AGENT-scope atomics (per-XCD L2s are not coherent for plain accesses).
// Replaces 7 dispatches (3 hist + 3 scan + quant) with 1.
__global__ __launch_bounds__(256) void select_kernel(const float4* __restrict__ w,
                                                     ushort4* __restrict__ wt,
                                                     int n4, SelState* st) {
  __shared__ unsigned int lh[4 * 2048];
  __shared__ unsigned int bc[2];      // bc[0]=prefix broadcast, bc[1]=is-last-block
  __shared__ unsigned int part[256];
  __shared__ unsigned int sh2[2];
  __shared__ unsigned int segbins[8];
  const int t = threadIdx.x;
  const int wb = t >> 6;
  unsigned int prefix = 0;

  for (int round = 0; round < 3; ++round) {
    const int nbins = (round == 0) ? 2048 : 1024;
    const int wbase = wb * nbins;
    for (int i = t; i < 4 * nbins; i += 256) lh[i] = 0;
    __syncthreads();
    int i = blockIdx.x * 256 + t;
    for (; i < n4; i += SEL_BLOCKS * 256) {
      float4 v = w[i];
#pragma unroll
      for (int c = 0; c < 4; ++c) {
        unsigned int u = __float_as_uint(((const float*)&v)[c]) & 0x7FFFFFFFu;
        if (round == 0) {
          atomicAdd(&lh[wbase + (u >> 20)], 1u);
        } else if (round == 1) {
          if ((u >> 20) == prefix) atomicAdd(&lh[wbase + ((u >> 10) & 1023u)], 1u);
        } else {
          if ((u >> 10) == prefix) atomicAdd(&lh[wbase + (u & 1023u)], 1u);
        }
      }
    }
    __syncthreads();
    unsigned int* gh = st->hist + round * 2048;
    for (int b = t; b < nbins; b += 256) {
      unsigned int c = lh[b] + lh[nbins + b] + lh[2 * nbins + b] + lh[3 * nbins + b];
      if (c) atomicAdd(&gh[b], c);
    }
    __threadfence();
    __syncthreads();
    if (t == 0) {
      unsigned int prev = __hip_atomic_fetch_add(&st->tickets[round], 1u,
                                                 __ATOMIC_ACQ_REL, __HIP_MEMORY_SCOPE_AGENT);
      bc[1] = (prev == SEL_BLOCKS - 1) ? 1u : 0u;
    }
    __syncthreads();
    if (bc[1]) {
      // Last block: scan gh for the bin holding the remaining-th smallest.
      const int per = nbins / 256;
      unsigned int s = 0;
      for (int q = 0; q < per; ++q)
        s += __hip_atomic_load(&gh[t * per + q], __ATOMIC_RELAXED, __HIP_MEMORY_SCOPE_AGENT);
      part[t] = s;
      __syncthreads();
      if (t == 0) {
        unsigned int rem = __hip_atomic_load(&st->remaining, __ATOMIC_RELAXED,
                                             __HIP_MEMORY_SCOPE_AGENT);
        int seg = 255;
        for (int q = 0; q < 256; ++q) {
          if (part[q] >= rem) { seg = q; break; }
          rem -= part[q];
        }
        sh2[0] = (unsigned int)seg;
        sh2[1] = rem;
      }
      __syncthreads();
      int seg = (int)sh2[0];
      if (t < per) segbins[t] = __hip_atomic_load(&gh[seg * per + t], __ATOMIC_RELAXED,
                                                  __HIP_MEMORY_SCOPE_AGENT);
      __syncthreads();
      if (t == 0) {
        unsigned int rem = sh2[1];
        int b = seg * per + per - 1;
        for (int q = 0; q < per; ++q) {
          unsigned int c = segbins[q];
          if (c >= rem) { b = seg * per + q; break; }
          rem -= c;
        }
        __hip_atomic_store(&st->remaining, rem, __ATOMIC_RELAXED, __HIP_MEMORY_SCOPE_AGENT);
        int width = (round == 0) ? 11 : 10;
        unsigned int np = (prefix << width) | (unsigned int)b;
        __hip_atomic_store(&st->prefix, np, __ATOMIC_RELAXED, __HIP_MEMORY_SCOPE_AGENT);
        __hip_atomic_store(&st->flags[round], 1u, __ATOMIC_RELEASE, __HIP_MEMORY_SCOPE_AGENT);
      }
    }
    if (t == 0) {
      while (__hip_atomic_load(&st->flags[round], __ATOMIC_ACQUIRE,
                               __HIP_MEMORY_SCOPE_AGENT) == 0u)
        __builtin_amdgcn_s_sleep(8);
      bc[0] = __hip_atomic_load(&st->prefix, __ATOMIC_RELAXED, __HIP_MEMORY_SCOPE_AGENT);
    }
    __syncthreads();
    prefix = bc[0];
  }

  // Quant phase: prefix is the 21-bit threshold pattern (strict >, bit-exact).
  const unsigned int thr = prefix;
  float lsum = 0.0f;
  unsigned int lcnt = 0;
  int i = blockIdx.x * 256 + t;
  for (; i < n4; i += SEL_BLOCKS * 256) {
    float4 v = w[i];
    ushort4 o;
    unsigned short* op = (unsigned short*)&o;
#pragma unroll
    for (int c = 0; c < 4; ++c) {
      unsigned int u = __float_as_uint(((const float*)&v)[c]);
      unsigned int a = u & 0x7FFFFFFFu;
      bool keep = a > thr;
      op[c] = keep ? (unsigned short)(0x3F80u | ((u >> 16) & 0x8000u)) : (unsigned short)0;
      if (keep) {
        lsum += __uint_as_float(a);
        lcnt++;
      }
    }
    wt[i] = o;
  }
#pragma unroll
  for (int off = 32; off > 0; off >>= 1) {
    lsum += __shfl_down(lsum, off);
    lcnt += __shfl_down(lcnt, off);
  }
  __shared__ float ssum[4];
  __shared__ unsigned int scnt[4];
  int lane = t & 63;
  if (lane == 0) { ssum[wb] = lsum; scnt[wb] = lcnt; }
  __syncthreads();
  if (t == 0) {
    float fs = ssum[0] + ssum[1] + ssum[2] + ssum[3];
    unsigned int fc = scnt[0] + scnt[1] + scnt[2] + scnt[3];
    atomicAdd(&st->sum, fs);
    atomicAdd(&st->count, fc);
  }
}

__device__ __forceinline__ void async_copy16(const unsigned short* g, unsigned short* l) {
  __builtin_amdgcn_global_load_lds(
      (const __attribute__((address_space(1))) void*)g,
      (__attribute__((address_space(3))) void*)l, 16, 0, 0);
}

// 256x256-tile GEMM, BK=32, 4 rotating LDS buffers (128 KiB), counted-vmcnt
// pipeline (3 tiles ahead, vmcnt(8) steady state), LDS XOR-swizzle (verified:
// bank conflicts 2.5e7 -> 0). This round: each K-tile split into TWO
// barrier-paired phases (stage-half + ds_read subtile + 16-MFMA cluster per
// phase) so waves drift between barriers -> one wave MFMAs while another
// reads LDS (role-split; what setprio arbitrates). Plus bijective XCD swizzle
// (512 wgs, 8 XCDs -> 4 contiguous tile-rows x 16 cols per XCD for A-panel L2
// reuse). 8 waves (2Mx4N), 128x64 output per wave.
// C[m][n] = scale * sum_k A[m][k]*B[n][k] + bias[n].
__global__ __launch_bounds__(512, 2)
void gemm_kernel(const unsigned short* __restrict__ A,
                 const unsigned short* __restrict__ B,
                 const float* __restrict__ bias,
                 const SelState* __restrict__ st,
                 float* __restrict__ C, int N) {
  constexpr int K = IN_F;
  constexpr int NT = K / 32;  // 128 K-tiles
  __shared__ __align__(16) unsigned short As[4][256 * 32];
  __shared__ __align__(16) unsigned short Bs[4][256 * 32];

  const int tid = threadIdx.x;
  const int wave = tid >> 6, lane = tid & 63;
  const int wm = wave >> 2, wn = wave & 3;   // 2x4 wave grid
  const int l16 = lane & 15, quad = lane >> 4;

  // T1: XCD-aware swizzle. Dispatch id -> XCD = id%8; give each XCD a
  // contiguous chunk of 64 tiles (4 tile-rows x 16 cols). 512 % 8 == 0 ->
  // simple form is bijective.
  const int id = blockIdx.y * gridDim.x + blockIdx.x;
  const int idsw = (id & 7) * 64 + (id >> 3);
  const int rowBase = (idsw >> 4) * 256;
  const int colBase = (idsw & 15) * 256;
  const unsigned short* Ag = A + (size_t)rowBase * K;
  const unsigned short* Bg = B + (size_t)colBase * K;

  // Staging: per tile 4 issues x 512 threads x 16B = 256 rows x 64 B.
  // Chunk id g: row g>>2, physical slot g&3 (LDS dest linear at g*16).
  // Source logical chunk = (g&3) ^ ((row>>1)&3)  [(g>>3)&3 == (row>>1)&3].
  const int g0 = tid;
  const int g1 = 512 + tid;
  const int c0 = ((g0 & 3) ^ ((g0 >> 3) & 3)) * 8;
  const int c1 = ((g1 & 3) ^ ((g1 >> 3) & 3)) * 8;
  const unsigned short* pA0 = Ag + (size_t)(g0 >> 2) * K + c0;
  const unsigned short* pA1 = Ag + (size_t)(g1 >> 2) * K + c1;
  const unsigned short* pB0 = Bg + (size_t)(g0 >> 2) * K + c0;
  const unsigned short* pB1 = Bg + (size_t)(g1 >> 2) * K + c1;

  // Read side: fragment row = base + l16 (base % 16 == 0) -> physical chunk =
  // quad ^ ((l16>>1)&3). Each 16-lane quarter covers all 32 banks exactly 2x.
  const int swz = (quad ^ ((l16 >> 1) & 3)) * 8;
  const int aoff = (wm * 128 + l16) * 32 + swz;
  const int boff = (wn * 64 + l16) * 32 + swz;

  f32x4 acc[8][4];
#pragma unroll
  for (int i = 0; i < 8; ++i)
#pragma unroll
    for (int j = 0; j < 4; ++j) acc[i][j] = {0.0f, 0.0f, 0.0f, 0.0f};

  // KTILE: two phases per K-tile.
  // Phase A: vmcnt(8)+lgkm(0) (tile t landed for me; my prior reads drained)
  //   -> barrier (tile t valid for all; buf w=(u+3)&3 free, its readers
  //   drained before everyone's pre-barrier lgkm(0)) -> stage A-half of tile
  //   t+3 -> ds_read af[0..3]+bfr[0..3] -> lgkm(0) -> 16 MFMA (i=0..3).
  // Phase B: barrier (role-split boundary) -> stage B-half -> ds_read
  //   af[4..7] -> lgkm(0) -> 16 MFMA (i=4..7). bfr stays live in VGPRs.
#define KTILE(t, u, VMASM, DOSTAGE) do {                                        \
    asm volatile(VMASM ::: "memory");                                           \
    __builtin_amdgcn_s_barrier();                                               \
    asm volatile("" ::: "memory");                                              \
    if (DOSTAGE) {                                                              \
      int ko = ((t) + 3) * 32;                                                  \
      async_copy16(pA0 + ko, &As[((u) + 3) & 3][g0 * 8]);                       \
      async_copy16(pA1 + ko, &As[((u) + 3) & 3][g1 * 8]);                       \
    }                                                                           \
    const unsigned short* Ab = As[(u)];                                         \
    const unsigned short* Bb = Bs[(u)];                                         \
    bf16x8 afA[4], bfr[4];                                                      \
    _Pragma("unroll")                                                           \
    for (int i = 0; i < 4; ++i) {                                               \
      afA[i] = __builtin_bit_cast(bf16x8, *(const short8*)(Ab + aoff + i * 512));\
      bfr[i] = __builtin_bit_cast(bf16x8, *(const short8*)(Bb + boff + i * 512));\
    }                                                                           \
    asm volatile("s_waitcnt lgkmcnt(0)" ::: "memory");                          \
    __builtin_amdgcn_s_setprio(1);                                              \
    _Pragma("unroll")                                                           \
    for (int i = 0; i < 4; ++i)                                                 \
      _Pragma("unroll")                                                         \
      for (int j = 0; j < 4; ++j)                                               \
        acc[i][j] = __builtin_amdgcn_mfma_f32_16x16x32_bf16(afA[i], bfr[j],     \
                                                            acc[i][j], 0, 0, 0);\
    __builtin_amdgcn_s_setprio(0);                                              \
    asm volatile("" ::: "memory");                                              \
    __builtin_amdgcn_s_barrier();                                               \
    asm volatile("" ::: "memory");                                              \
    if (DOSTAGE) {                                                              \
      int ko = ((t) + 3) * 32;                                                  \
      async_copy16(pB0 + ko, &Bs[((u) + 3) & 3][g0 * 8]);                       \
      async_copy16(pB1 + ko, &Bs[((u) + 3) & 3][g1 * 8]);                       \
    }                                                                           \
    bf16x8 afB[4];                                                              \
    _Pragma("unroll")                                                           \
    for (int i = 0; i < 4; ++i)                                                 \
      afB[i] = __builtin_bit_cast(bf16x8,                                       \
                                  *(const short8*)(Ab + aoff + (i + 4) * 512)); \
    asm volatile("s_waitcnt lgkmcnt(0)" ::: "memory");                          \
    __builtin_amdgcn_s_setprio(1);                                              \
    _Pragma("unroll")                                                           \
    for (int i = 0; i < 4; ++i)                                                 \
      _Pragma("unroll")                                                         \
      for (int j = 0; j < 4; ++j)                                               \
        acc[i + 4][j] = __builtin_amdgcn_mfma_f32_16x16x32_bf16(afB[i], bfr[j], \
                                                                acc[i + 4][j],  \
                                                                0, 0, 0);       \
    __builtin_amdgcn_s_setprio(0);                                              \
  } while (0)

#define STAGE(buf, t) do {                                   \
    int ko = (t) * 32;                                       \
    async_copy16(pA0 + ko, &As[(buf)][g0 * 8]);              \
    async_copy16(pA1 + ko, &As[(buf)][g1 * 8]);              \
    async_copy16(pB0 + ko, &Bs[(buf)][g0 * 8]);              \
    async_copy16(pB1 + ko, &Bs[(buf)][g1 * 8]);              \
  } while (0)

  // Prologue: 3 tiles in flight (12 outstanding loads per thread).
  STAGE(0, 0);
  STAGE(1, 1);
  STAGE(2, 2);

  // Steady state: 12 outstanding -> vmcnt(8) proves the oldest tile landed.
  for (int tt = 0; tt <= NT - 8; tt += 4) {
    KTILE(tt + 0, 0, "s_waitcnt vmcnt(8) lgkmcnt(0)", true);
    KTILE(tt + 1, 1, "s_waitcnt vmcnt(8) lgkmcnt(0)", true);
    KTILE(tt + 2, 2, "s_waitcnt vmcnt(8) lgkmcnt(0)", true);
    KTILE(tt + 3, 3, "s_waitcnt vmcnt(8) lgkmcnt(0)", true);
  }
  // Tail: stage last tile, then drain 8 -> 4 -> 0.
  KTILE(NT - 4, 0, "s_waitcnt vmcnt(8) lgkmcnt(0)", true);
  KTILE(NT - 3, 1, "s_waitcnt vmcnt(8) lgkmcnt(0)", false);
  KTILE(NT - 2, 2, "s_waitcnt vmcnt(4) lgkmcnt(0)", false);
  KTILE(NT - 1, 3, "s_waitcnt vmcnt(0) lgkmcnt(0)", false);

#undef KTILE
#undef STAGE

  // scale computed inline (identical fp32 division to reference finalize).
  unsigned int cnt = st->count;
  float scale = st->sum / (float)(cnt ? cnt : 1u);
  float bv[4];
#pragma unroll
  for (int j = 0; j < 4; ++j) bv[j] = bias[colBase + wn * 64 + j * 16 + l16];
#pragma unroll
  for (int i = 0; i < 8; ++i) {
    int row0 = rowBase + wm * 128 + i * 16 + quad * 4;
#pragma unroll
    for (int j = 0; j < 4; ++j) {
      int col = colBase + wn * 64 + j * 16 + l16;
#pragma unroll
      for (int r = 0; r < 4; ++r) {
        C[(size_t)(row0 + r) * N + col] = scale * acc[i][j][r] + bv[j];
      }
    }
  }
}

extern "C" void kernel_launch(void* const* d_in, const int* in_sizes, int n_in,
                              void* d_out, int out_size, void* d_ws, size_t ws_size,
                              hipStream_t stream) {
  const float* x = (const float*)d_in[0];
  const float* w = (const float*)d_in[1];
  const float* bias = (const float*)d_in[2];
  float* out = (float*)d_out;
  const int K = IN_F, N = OUT_F;
  const int n_w = in_sizes[1];            // 4096*4096
  const int n_x = in_sizes[0];            // 4*2048*4096
  const int M = n_x / K;                  // 8192
  const unsigned int k = (unsigned int)(n_w / 2);  // int(n * 0.5), 1-indexed kth

  char* ws = (char*)d_ws;
  SelState* st = (SelState*)ws;
  unsigned short* wt = (unsigned short*)(ws + 65536);                              // 32 MB
  unsigned short* xb = (unsigned short*)(ws + 65536 + (size_t)N * K * 2);          // 64 MB

  hipLaunchKernelGGL(cast_x_kernel, dim3(4096), dim3(256), 0, stream,
                     (const float4*)x, (ushort4*)xb, n_x / 4, st, k);
  hipLaunchKernelGGL(select_kernel, dim3(SEL_BLOCKS), dim3(256), 0, stream,
                     (const float4*)w, (ushort4*)wt, n_w / 4, st);
  hipLaunchKernelGGL(gemm_kernel, dim3(N / 256, M / 256), dim3(512), 0, stream,
                     xb, wt, bias, st, out, N);
}